// Round 1
// baseline (349.282 us; speedup 1.0000x reference)
//
#include <hip/hip_runtime.h>
#include <math.h>

#define BB 16
#define SS 4096
#define HH 1024

// ---------------------------------------------------------------------------
// Kernel A: scores[b,j] = mask[b] * dot(hidden[b, start+j, :], w), j < qlen[b]
// One wave (64 lanes) per row; w held in 16 regs/lane; float4 coalesced.
// ---------------------------------------------------------------------------
__global__ __launch_bounds__(256) void score_kernel(
    const float* __restrict__ hidden,
    const int*   __restrict__ qidx,
    const float* __restrict__ mask,
    const float* __restrict__ w,
    float*       __restrict__ scores)
{
    const int b     = blockIdx.y;
    const int start = qidx[2 * b];
    const int qlen  = qidx[2 * b + 1] - start;
    const int j0    = blockIdx.x * 64;            // 64 rows per block (16/wave)
    if (j0 >= qlen) return;

    const int lane = threadIdx.x & 63;
    const int wave = threadIdx.x >> 6;

    float4 wreg[4];
#pragma unroll
    for (int k = 0; k < 4; ++k)
        wreg[k] = ((const float4*)w)[lane + 64 * k];

    const float mb = mask[b];

    for (int r = 0; r < 16; ++r) {
        const int j = j0 + wave * 16 + r;
        if (j >= qlen) break;
        const float4* row =
            (const float4*)(hidden + ((size_t)b * SS + start + j) * HH);
        float acc = 0.f;
#pragma unroll
        for (int k = 0; k < 4; ++k) {
            float4 hv = row[lane + 64 * k];
            acc += hv.x * wreg[k].x + hv.y * wreg[k].y +
                   hv.z * wreg[k].z + hv.w * wreg[k].w;
        }
#pragma unroll
        for (int off = 32; off > 0; off >>= 1)
            acc += __shfl_down(acc, off, 64);
        if (lane == 0) scores[b * SS + j] = acc * mb;
    }
}

// ---------------------------------------------------------------------------
// Kernel B: per-b softmax stats. m = max(0, max_j s_j) (zero slots always
// included since max_len - qlen >= 1). denom includes (max_len-qlen)*exp(-m).
// Overwrites scores with final weights exp(s-m)*mask/denom. Zeroes d_out[b].
// ---------------------------------------------------------------------------
__global__ __launch_bounds__(256) void softmax_kernel(
    const int*   __restrict__ qidx,
    const float* __restrict__ mask,
    float*       __restrict__ scores,
    float*       __restrict__ out)
{
    const int b     = blockIdx.x;
    const int start = qidx[2 * b];
    const int qlen  = qidx[2 * b + 1] - start;

    int max_len = 0;
    for (int i = 0; i < BB; ++i) {
        int l = qidx[2 * i + 1] - qidx[2 * i];
        max_len = max(max_len, l);
    }
    max_len += 1;

    const int tid  = threadIdx.x;
    const int lane = tid & 63;
    const int wave = tid >> 6;

    // zero this batch's output (re-poisoned to 0xAA before every timed call)
    ((float4*)out)[b * (HH / 4) + tid] = make_float4(0.f, 0.f, 0.f, 0.f);

    __shared__ float red[8];

    // --- max reduce over valid scores ---
    float m = -INFINITY;
    for (int j = tid; j < qlen; j += 256) m = fmaxf(m, scores[b * SS + j]);
#pragma unroll
    for (int off = 32; off > 0; off >>= 1)
        m = fmaxf(m, __shfl_down(m, off, 64));
    if (lane == 0) red[wave] = m;
    __syncthreads();
    if (tid == 0) {
        float mm = fmaxf(fmaxf(red[0], red[1]), fmaxf(red[2], red[3]));
        red[0] = fmaxf(mm, 0.f);   // zero-score slots always present
    }
    __syncthreads();
    m = red[0];
    __syncthreads();

    // --- sum of exp ---
    float s = 0.f;
    for (int j = tid; j < qlen; j += 256) s += __expf(scores[b * SS + j] - m);
#pragma unroll
    for (int off = 32; off > 0; off >>= 1) s += __shfl_down(s, off, 64);
    if (lane == 0) red[wave] = s;
    __syncthreads();
    if (tid == 0) {
        float denom = red[0] + red[1] + red[2] + red[3];
        denom += (float)(max_len - qlen) * __expf(-m);
        red[4] = mask[b] / denom;
    }
    __syncthreads();
    const float scale = red[4];

    // --- overwrite scores with final weights ---
    for (int j = tid; j < qlen; j += 256)
        scores[b * SS + j] = __expf(scores[b * SS + j] - m) * scale;
}

// ---------------------------------------------------------------------------
// Kernel C: out[b,h] += sum_j weight[b,j] * hidden[b,start+j,h]
// 32 rows per block; thread t owns h = 4t..4t+3 (float4, coalesced);
// register accumulation then 4 atomicAdds per thread.
// ---------------------------------------------------------------------------
__global__ __launch_bounds__(256) void agg_kernel(
    const float* __restrict__ hidden,
    const int*   __restrict__ qidx,
    const float* __restrict__ weights,
    float*       __restrict__ out)
{
    const int b     = blockIdx.y;
    const int start = qidx[2 * b];
    const int qlen  = qidx[2 * b + 1] - start;
    const int j0    = blockIdx.x * 32;
    if (j0 >= qlen) return;
    const int jend = min(j0 + 32, qlen);
    const int tid  = threadIdx.x;

    float4 acc = make_float4(0.f, 0.f, 0.f, 0.f);
    for (int j = j0; j < jend; ++j) {
        const float wt = weights[b * SS + j];
        float4 hv = ((const float4*)(hidden + ((size_t)b * SS + start + j) * HH))[tid];
        acc.x += wt * hv.x;
        acc.y += wt * hv.y;
        acc.z += wt * hv.z;
        acc.w += wt * hv.w;
    }
    float* o = out + b * HH + tid * 4;
    atomicAdd(o + 0, acc.x);
    atomicAdd(o + 1, acc.y);
    atomicAdd(o + 2, acc.z);
    atomicAdd(o + 3, acc.w);
}

extern "C" void kernel_launch(void* const* d_in, const int* in_sizes, int n_in,
                              void* d_out, int out_size, void* d_ws, size_t ws_size,
                              hipStream_t stream)
{
    const float* hidden = (const float*)d_in[0];
    const int*   qidx   = (const int*)d_in[1];   // int64 in ref -> int32 per harness
    const float* mask   = (const float*)d_in[2];
    const float* w      = (const float*)d_in[3];
    float*       out    = (float*)d_out;
    float*       scores = (float*)d_ws;          // BB*SS floats = 256 KB

    score_kernel<<<dim3(SS / 64, BB), 256, 0, stream>>>(hidden, qidx, mask, w, scores);
    softmax_kernel<<<BB, 256, 0, stream>>>(qidx, mask, scores, out);
    agg_kernel<<<dim3(SS / 32, BB), 256, 0, stream>>>(hidden, qidx, scores, out);
}

// Round 2
// 345.932 us; speedup vs baseline: 1.0097x; 1.0097x over previous
//
#include <hip/hip_runtime.h>
#include <math.h>

#define BB 16
#define SS 4096
#define HH 1024

// ---------------------------------------------------------------------------
// Kernel A: scores[b,j] = mask[b] * dot(hidden[b, start+j, :], w), j < qlen[b]
// ONE ROW PER WAVE (4 rows/block) for ~5.5K active waves -> latency hidden by
// TLP. Lane i covers h = {i, i+64, i+128, i+192} as float4s; shuffle-reduce.
// ---------------------------------------------------------------------------
__global__ __launch_bounds__(256) void score_kernel(
    const float* __restrict__ hidden,
    const int*   __restrict__ qidx,
    const float* __restrict__ mask,
    const float* __restrict__ w,
    float*       __restrict__ scores)
{
    const int b     = blockIdx.y;
    const int start = qidx[2 * b];
    const int qlen  = qidx[2 * b + 1] - start;
    const int lane  = threadIdx.x & 63;
    const int wave  = threadIdx.x >> 6;
    const int j     = blockIdx.x * 4 + wave;
    if (blockIdx.x * 4 >= qlen) return;   // whole block idle
    if (j >= qlen) return;                // partial block tail

    const float4* row =
        (const float4*)(hidden + ((size_t)b * SS + start + j) * HH);
    const float4* wv = (const float4*)w;

    float acc = 0.f;
#pragma unroll
    for (int k = 0; k < 4; ++k) {
        float4 hv = row[lane + 64 * k];
        float4 wr = wv[lane + 64 * k];
        acc += hv.x * wr.x + hv.y * wr.y + hv.z * wr.z + hv.w * wr.w;
    }
#pragma unroll
    for (int off = 32; off > 0; off >>= 1)
        acc += __shfl_down(acc, off, 64);
    if (lane == 0) scores[b * SS + j] = acc * mask[b];
}

// ---------------------------------------------------------------------------
// Kernel B: per-b softmax stats. m = max(0, max_j s_j) (zero-score slots are
// always present since max_len - qlen >= 1). denom += (max_len-qlen)*exp(-m).
// Overwrites scores with final weights exp(s-m)*mask/denom. Zeroes d_out[b].
// ---------------------------------------------------------------------------
__global__ __launch_bounds__(256) void softmax_kernel(
    const int*   __restrict__ qidx,
    const float* __restrict__ mask,
    float*       __restrict__ scores,
    float*       __restrict__ out)
{
    const int b     = blockIdx.x;
    const int start = qidx[2 * b];
    const int qlen  = qidx[2 * b + 1] - start;

    int max_len = 0;
    for (int i = 0; i < BB; ++i) {
        int l = qidx[2 * i + 1] - qidx[2 * i];
        max_len = max(max_len, l);
    }
    max_len += 1;

    const int tid  = threadIdx.x;
    const int lane = tid & 63;
    const int wave = tid >> 6;

    // zero this batch's output (harness poisons d_out to 0xAA pre-launch)
    ((float4*)out)[b * (HH / 4) + tid] = make_float4(0.f, 0.f, 0.f, 0.f);

    __shared__ float red[8];

    // --- max over valid scores ---
    float m = -INFINITY;
    for (int j = tid; j < qlen; j += 256) m = fmaxf(m, scores[b * SS + j]);
#pragma unroll
    for (int off = 32; off > 0; off >>= 1)
        m = fmaxf(m, __shfl_down(m, off, 64));
    if (lane == 0) red[wave] = m;
    __syncthreads();
    if (tid == 0) {
        float mm = fmaxf(fmaxf(red[0], red[1]), fmaxf(red[2], red[3]));
        red[0] = fmaxf(mm, 0.f);   // zero-score slots always present
    }
    __syncthreads();
    m = red[0];
    __syncthreads();

    // --- sum of exp ---
    float s = 0.f;
    for (int j = tid; j < qlen; j += 256) s += __expf(scores[b * SS + j] - m);
#pragma unroll
    for (int off = 32; off > 0; off >>= 1) s += __shfl_down(s, off, 64);
    if (lane == 0) red[wave] = s;
    __syncthreads();
    if (tid == 0) {
        float denom = red[0] + red[1] + red[2] + red[3];
        denom += (float)(max_len - qlen) * __expf(-m);
        red[4] = mask[b] / denom;
    }
    __syncthreads();
    const float scale = red[4];

    // --- overwrite scores with final weights ---
    for (int j = tid; j < qlen; j += 256)
        scores[b * SS + j] = __expf(scores[b * SS + j] - m) * scale;
}

// ---------------------------------------------------------------------------
// Kernel C: out[b,h] += sum_j weight[b,j] * hidden[b,start+j,h]
// 16 rows per block (~1380 active blocks, ~5.4/CU). Thread t owns h=4t..4t+3
// (float4, coalesced); register accumulation; 4 atomicAdds per thread
// (~86 atomics/address total -- negligible contention).
// ---------------------------------------------------------------------------
__global__ __launch_bounds__(256) void agg_kernel(
    const float* __restrict__ hidden,
    const int*   __restrict__ qidx,
    const float* __restrict__ weights,
    float*       __restrict__ out)
{
    const int b     = blockIdx.y;
    const int start = qidx[2 * b];
    const int qlen  = qidx[2 * b + 1] - start;
    const int j0    = blockIdx.x * 16;
    if (j0 >= qlen) return;
    const int jend = min(j0 + 16, qlen);
    const int tid  = threadIdx.x;

    const float4* base =
        (const float4*)(hidden + ((size_t)b * SS + start) * HH) + tid;

    float4 acc = make_float4(0.f, 0.f, 0.f, 0.f);
#pragma unroll 4
    for (int j = j0; j < jend; ++j) {
        const float wt = weights[b * SS + j];
        float4 hv = base[(size_t)j * (HH / 4)];
        acc.x += wt * hv.x;
        acc.y += wt * hv.y;
        acc.z += wt * hv.z;
        acc.w += wt * hv.w;
    }
    float* o = out + b * HH + tid * 4;
    atomicAdd(o + 0, acc.x);
    atomicAdd(o + 1, acc.y);
    atomicAdd(o + 2, acc.z);
    atomicAdd(o + 3, acc.w);
}

extern "C" void kernel_launch(void* const* d_in, const int* in_sizes, int n_in,
                              void* d_out, int out_size, void* d_ws, size_t ws_size,
                              hipStream_t stream)
{
    const float* hidden = (const float*)d_in[0];
    const int*   qidx   = (const int*)d_in[1];
    const float* mask   = (const float*)d_in[2];
    const float* w      = (const float*)d_in[3];
    float*       out    = (float*)d_out;
    float*       scores = (float*)d_ws;          // BB*SS floats = 256 KB

    score_kernel<<<dim3(SS / 4, BB), 256, 0, stream>>>(hidden, qidx, mask, w, scores);
    softmax_kernel<<<BB, 256, 0, stream>>>(qidx, mask, scores, out);
    agg_kernel<<<dim3(SS / 16, BB), 256, 0, stream>>>(hidden, qidx, scores, out);
}

// Round 4
// 314.119 us; speedup vs baseline: 1.1119x; 1.1013x over previous
//
#include <hip/hip_runtime.h>
#include <math.h>

#define BB 16
#define SS 4096
#define HH 1024
#define CH 64          // chunks (blocks) per batch
#define NWB (CH * 4)   // waves per batch

// ---------------------------------------------------------------------------
// Pass 1 (single pass over hidden): wave handles rows j = wid, wid+NWB, ...
// For each row: dot with w (row held in 16 regs), shuffle-reduce + broadcast,
// e = exp(mask*dot); accumulate e (denominator, wave-uniform -> tracked once)
// and e*h (numerator, per-lane columns) in registers. Block-reduce the 4
// waves via LDS, write one 1024-float partial + 1 den per block to ws.
// No max-subtraction: |mask*dot| <~ 6 so exp is safely in fp32 range
// (softmax max-shift is an exact rescale in real arithmetic).
// BUG FIXED vs R3: dacc is wave-uniform after the broadcast; the old code
// additionally wave-reduced it -> denominator 64x too large -> out ~ 0.
// ---------------------------------------------------------------------------
__global__ __launch_bounds__(256) void pass1_kernel(
    const float* __restrict__ hidden,
    const int*   __restrict__ qidx,
    const float* __restrict__ mask,
    const float* __restrict__ w,
    float4*      __restrict__ pnum,   // [BB*CH*256] float4
    float*       __restrict__ pden)   // [BB*CH]
{
    const int b     = blockIdx.y;
    const int start = qidx[2 * b];
    const int qlen  = qidx[2 * b + 1] - start;
    const int lane  = threadIdx.x & 63;
    const int wave  = threadIdx.x >> 6;
    const int wid   = blockIdx.x * 4 + wave;
    const float mb  = mask[b];

    float4 wreg[4];
#pragma unroll
    for (int k = 0; k < 4; ++k)
        wreg[k] = ((const float4*)w)[lane + 64 * k];

    float4 acc[4];
#pragma unroll
    for (int k = 0; k < 4; ++k) acc[k] = make_float4(0.f, 0.f, 0.f, 0.f);
    float dacc = 0.f;   // wave-uniform sum of e over this wave's rows

    for (int j = wid; j < qlen; j += NWB) {
        const float4* row =
            (const float4*)(hidden + ((size_t)b * SS + start + j) * HH);
        float4 hv[4];
        float s = 0.f;
#pragma unroll
        for (int k = 0; k < 4; ++k) {
            hv[k] = row[lane + 64 * k];
            s += hv[k].x * wreg[k].x + hv[k].y * wreg[k].y +
                 hv[k].z * wreg[k].z + hv[k].w * wreg[k].w;
        }
#pragma unroll
        for (int off = 32; off > 0; off >>= 1)
            s += __shfl_down(s, off, 64);
        s = __shfl(s, 0, 64);                 // broadcast full dot to all lanes
        const float e = __expf(s * mb);
        dacc += e;                            // same value on every lane
#pragma unroll
        for (int k = 0; k < 4; ++k) {
            acc[k].x += e * hv[k].x;
            acc[k].y += e * hv[k].y;
            acc[k].z += e * hv[k].z;
            acc[k].w += e * hv[k].w;
        }
    }

    // --- block reduce: 4 waves -> one 1024-float partial ---
    __shared__ float4 lred[4][256];           // 16 KB
#pragma unroll
    for (int k = 0; k < 4; ++k)
        lred[wave][lane + 64 * k] = acc[k];

    __shared__ float dred[4];
    if (lane == 0) dred[wave] = dacc;         // dacc already wave-total: NO reduce
    __syncthreads();

    const int t = threadIdx.x;
    float4 s0 = lred[0][t], s1 = lred[1][t], s2 = lred[2][t], s3 = lred[3][t];
    float4 sum = make_float4(s0.x + s1.x + s2.x + s3.x,
                             s0.y + s1.y + s2.y + s3.y,
                             s0.z + s1.z + s2.z + s3.z,
                             s0.w + s1.w + s2.w + s3.w);
    pnum[((size_t)b * CH + blockIdx.x) * 256 + t] = sum;
    if (t == 0)
        pden[b * CH + blockIdx.x] = dred[0] + dred[1] + dred[2] + dred[3];
}

// ---------------------------------------------------------------------------
// Pass 2: out[b, 4t..4t+3] = mask[b] * sum_c pnum[b,c,t] / denom_b
// denom_b = sum_c pden[b,c] + (max_len - qlen_b) * exp(0)
// ---------------------------------------------------------------------------
__global__ __launch_bounds__(256) void pass2_kernel(
    const int*    __restrict__ qidx,
    const float*  __restrict__ mask,
    const float4* __restrict__ pnum,
    const float*  __restrict__ pden,
    float4*       __restrict__ out)
{
    const int b = blockIdx.x;
    const int t = threadIdx.x;

    int max_len = 0;
    for (int i = 0; i < BB; ++i) {
        int l = qidx[2 * i + 1] - qidx[2 * i];
        max_len = max(max_len, l);
    }
    max_len += 1;
    const int qlen = qidx[2 * b + 1] - qidx[2 * b];

    float4 sum = make_float4(0.f, 0.f, 0.f, 0.f);
    float den = 0.f;
#pragma unroll 8
    for (int c = 0; c < CH; ++c) {
        float4 p = pnum[((size_t)b * CH + c) * 256 + t];
        sum.x += p.x; sum.y += p.y; sum.z += p.z; sum.w += p.w;
        den += pden[b * CH + c];
    }
    den += (float)(max_len - qlen);           // zero-score slots, exp(0)=1
    const float scale = mask[b] / den;
    out[b * 256 + t] = make_float4(sum.x * scale, sum.y * scale,
                                   sum.z * scale, sum.w * scale);
}

extern "C" void kernel_launch(void* const* d_in, const int* in_sizes, int n_in,
                              void* d_out, int out_size, void* d_ws, size_t ws_size,
                              hipStream_t stream)
{
    const float* hidden = (const float*)d_in[0];
    const int*   qidx   = (const int*)d_in[1];
    const float* mask   = (const float*)d_in[2];
    const float* w      = (const float*)d_in[3];

    float4* pnum = (float4*)d_ws;                                      // 4 MB
    float*  pden = (float*)((char*)d_ws + (size_t)BB * CH * 256 * 16); // 4 KB
    float4* out  = (float4*)d_out;

    pass1_kernel<<<dim3(CH, BB), 256, 0, stream>>>(hidden, qidx, mask, w, pnum, pden);
    pass2_kernel<<<BB, 256, 0, stream>>>(qidx, mask, pnum, pden, out);
}